// Round 12
// baseline (177.203 us; speedup 1.0000x reference)
//
#include <hip/hip_runtime.h>
#include <math.h>

#define Gn 64
#define Nn 1000
#define En 8192
#define Cc 128
#define HIDn 256
#define EPSf 1e-5f

typedef __attribute__((ext_vector_type(8))) short bh8;
typedef __attribute__((ext_vector_type(4))) float fx4;

__device__ __forceinline__ unsigned short f2bf(float f) {
    unsigned u = __float_as_uint(f);
    u += 0x7fffu + ((u >> 16) & 1u);
    return (unsigned short)(u >> 16);
}
__device__ __forceinline__ float bflo(unsigned u) { return __uint_as_float(u << 16); }
__device__ __forceinline__ float bfhi(unsigned u) { return __uint_as_float(u & 0xffff0000u); }

// ---- pre: blocks 0..63 prep(graph b) | block 64: W0->Wt0g bf16^T | block 65: W1->Wt1g ----
__global__ __launch_bounds__(256) void k_pre(const int* __restrict__ ei,
                                             const float* __restrict__ W0, const float* __restrict__ W1,
                                             int4* __restrict__ ninfo, int2* __restrict__ epair,
                                             float* __restrict__ pooled, float* __restrict__ repr,
                                             int* __restrict__ ctr,
                                             unsigned short* __restrict__ Wt0g,
                                             unsigned short* __restrict__ Wt1g)
{
    __shared__ int   curs[1024];
    __shared__ float dinv_s[1024];
    __shared__ int   wsum[4];
    __shared__ __align__(16) short Wls[128][136];
    int t = threadIdx.x;

    if (blockIdx.x >= 64) {
        // ---- transpose + convert one weight matrix: W[k][n] fp32 -> Wt[n][k] bf16 ----
        const float* Wsrc = (blockIdx.x == 64) ? W0 : W1;
        unsigned short* Wdst = (blockIdx.x == 64) ? Wt0g : Wt1g;
        for (int idx = t; idx < 16384; idx += 256) {
            int kI = idx >> 7, n = idx & 127;
            Wls[n][kI] = (short)f2bf(Wsrc[idx]);
        }
        __syncthreads();
        for (int idx = t; idx < 2048; idx += 256) {       // 2048 chunks of 8 shorts
            int n = idx >> 4, kc = idx & 15;
            bh8 v = *(const bh8*)&Wls[n][kc * 8];
            *(bh8*)(Wdst + (size_t)idx * 8) = v;          // row-major [n][k]
        }
        return;
    }

    // ---------------- prep (256 threads, wave-scan CSR build) ----------------
    int g = blockIdx.x;
    const int* srcp = ei + (size_t)g * 2 * En;
    const int* dstp = srcp + En;
    int lane = t & 63, wv = t >> 6;

    #pragma unroll
    for (int j = 0; j < 4; ++j) curs[t * 4 + j] = 0;
    __syncthreads();
    for (int e = t; e < En; e += 256) atomicAdd(&curs[dstp[e]], 1);
    __syncthreads();

    int base = t * 4;
    int d0 = curs[base], d1 = curs[base + 1], d2 = curs[base + 2], d3 = curs[base + 3];
    int s = d0 + d1 + d2 + d3;
    int v = s;
    #pragma unroll
    for (int off = 1; off <= 32; off <<= 1) {
        int u = __shfl_up(v, off);
        if (lane >= off) v += u;
    }
    if (lane == 63) wsum[wv] = v;
    __syncthreads();
    int woff = 0;
    #pragma unroll
    for (int w = 0; w < 4; ++w) if (w < wv) woff += wsum[w];
    int e0 = woff + v - s;
    int e1 = e0 + d0, e2 = e1 + d1, e3 = e2 + d2;
    float dv0 = rsqrtf((float)d0 + 1.f), dv1 = rsqrtf((float)d1 + 1.f);
    float dv2 = rsqrtf((float)d2 + 1.f), dv3 = rsqrtf((float)d3 + 1.f);
    curs[base] = e0; curs[base + 1] = e1; curs[base + 2] = e2; curs[base + 3] = e3;
    dinv_s[base] = dv0; dinv_s[base + 1] = dv1; dinv_s[base + 2] = dv2; dinv_s[base + 3] = dv3;
    if (base < Nn)     ninfo[g * Nn + base]     = make_int4(e0, d0, __float_as_int(dv0 * dv0), 0);
    if (base + 1 < Nn) ninfo[g * Nn + base + 1] = make_int4(e1, d1, __float_as_int(dv1 * dv1), 0);
    if (base + 2 < Nn) ninfo[g * Nn + base + 2] = make_int4(e2, d2, __float_as_int(dv2 * dv2), 0);
    if (base + 3 < Nn) ninfo[g * Nn + base + 3] = make_int4(e3, d3, __float_as_int(dv3 * dv3), 0);
    __syncthreads();

    for (int e = t; e < En; e += 256) {
        int dd = dstp[e], ss = srcp[e];
        int p = atomicAdd(&curs[dd], 1);
        float w = dinv_s[ss] * dinv_s[dd];
        epair[(size_t)g * En + p] = make_int2(ss, __float_as_int(w));
    }
    if (t < Cc) pooled[g * Cc + t] = 0.f;      // accumulated by k_combine<1>
    if (g == 0 && t < Cc) repr[t] = 0.f;       // accumulated by k_tailfinal
    if (g == 0 && t == 0) *ctr = 0;            // completion counter for k_tailfinal
}

// ------ gemm: H[g] = bf16(X[g] @ W), 16 blocks/graph (1024 total), pre-transposed bf16 W ----
// INBF=0: X fp32; INBF=1: X bf16 (T buffer)
template<int INBF>
__global__ __launch_bounds__(256) void k_gemm(const void* __restrict__ Xin,
                                              const unsigned short* __restrict__ Wtg,
                                              unsigned short* __restrict__ Hout)
{
    __shared__ __align__(16) short Wt[128][136];
    int b = blockIdx.x;
    int xcd = b & 7, gg = (b >> 3) & 7, rblk = b >> 6;   // graph g on XCD g%8; rblk 0..15
    int g = xcd + 8 * gg;
    int t = threadIdx.x;
    // stage pre-transposed W (bf16): straight vector copy, no conversion
    for (int idx = t; idx < 2048; idx += 256) {
        int n = idx >> 4, kc = idx & 15;
        bh8 v = *(const bh8*)(Wtg + (size_t)idx * 8);
        *(bh8*)&Wt[n][kc * 8] = v;
    }
    __syncthreads();

    int wave = t >> 6, l = t & 63;
    int lr = l & 15, lg = l >> 4;
    const float* Xf = (const float*)Xin + (size_t)g * Nn * Cc;
    const short* Xh = (const short*)Xin + (size_t)g * Nn * Cc;
    unsigned short* Hg = Hout + (size_t)g * Nn * Cc;

    int rbase = rblk * 64 + wave * 16;
    int r = rbase + lr;
    bool ok = r < Nn;
    bh8 af[4];
    if (INBF) {
        #pragma unroll
        for (int ks = 0; ks < 4; ++ks) {
            if (ok) af[ks] = *(const bh8*)(Xh + (size_t)r * Cc + ks * 32 + lg * 8);
            else    af[ks] = bh8{0, 0, 0, 0, 0, 0, 0, 0};
        }
    } else {
        #pragma unroll
        for (int ks = 0; ks < 4; ++ks) {
            if (ok) {
                const float* xp = Xf + (size_t)r * Cc + ks * 32 + lg * 8;
                fx4 a0 = *(const fx4*)xp;
                fx4 a1 = *(const fx4*)(xp + 4);
                bh8 av;
                av[0] = (short)f2bf(a0[0]); av[1] = (short)f2bf(a0[1]);
                av[2] = (short)f2bf(a0[2]); av[3] = (short)f2bf(a0[3]);
                av[4] = (short)f2bf(a1[0]); av[5] = (short)f2bf(a1[1]);
                av[6] = (short)f2bf(a1[2]); av[7] = (short)f2bf(a1[3]);
                af[ks] = av;
            } else af[ks] = bh8{0, 0, 0, 0, 0, 0, 0, 0};
        }
    }
    fx4 acc[8];
    #pragma unroll
    for (int ct = 0; ct < 8; ++ct) acc[ct] = fx4{0.f, 0.f, 0.f, 0.f};
    #pragma unroll
    for (int ks = 0; ks < 4; ++ks) {
        #pragma unroll
        for (int ct = 0; ct < 8; ++ct) {
            bh8 bfr = *(const bh8*)(&Wt[ct * 16 + lr][ks * 32 + lg * 8]);
            acc[ct] = __builtin_amdgcn_mfma_f32_16x16x32_bf16(af[ks], bfr, acc[ct], 0, 0, 0);
        }
    }
    // C/D layout: col = ct*16 + (lane&15), row = rbase + (lane>>4)*4 + reg
    #pragma unroll
    for (int ct = 0; ct < 8; ++ct) {
        #pragma unroll
        for (int rg = 0; rg < 4; ++rg) {
            int row = rbase + lg * 4 + rg;
            if (row < Nn) Hg[(size_t)row * Cc + ct * 16 + lr] = f2bf(acc[ct][rg]);
        }
    }
}

// -- combine: tanh(b + selfw*H[n] + sum_e w_e*H[src_e]); two-node interleave, 8 load chains --
template<int POOL>
__global__ __launch_bounds__(256) void k_combine(const unsigned* __restrict__ Hb, const int2* __restrict__ epair,
                                                 const int4* __restrict__ ninfo, const float* __restrict__ bias,
                                                 unsigned* __restrict__ Tout, float* __restrict__ pooled)
{
    int b = blockIdx.x;
    int xcd = b & 7, j = b >> 3;
    int g = xcd + 8 * (j & 7);     // same XCD as this graph's GEMM blocks
    int blk = j >> 3;              // 0..31
    int wave = threadIdx.x >> 6, lane = threadIdx.x & 63;
    const unsigned* Hg = Hb + (size_t)g * Nn * 64;   // rows of 64 uint = 128 bf16
    const int2* epg = epair + (size_t)g * En;
    const int4* nig = ninfo + (size_t)g * Nn;
    float2 bb = *(const float2*)(bias + lane * 2);
    float px = 0.f, py = 0.f;
    int pid = blk * 4 + wave;                        // pair id 0..127

    for (int n0 = pid * 2; n0 < Nn; n0 += 256) {
        int n1 = n0 + 1;                             // Nn even -> n1 always valid
        int4 ni0 = nig[n0];
        int4 ni1 = nig[n1];
        int st0 = ni0.x, dc0 = ni0.y;
        int st1 = ni1.x, dc1 = ni1.y;
        float sw0 = __int_as_float(ni0.z);
        float sw1 = __int_as_float(ni1.z);
        unsigned hv0 = Hg[(size_t)n0 * 64 + lane];
        unsigned hv1 = Hg[(size_t)n1 * 64 + lane];
        // node0 accumulators (a*), node1 accumulators (c*): same per-node grouping as before
        float a0x = bflo(hv0) * sw0 + bb.x, a0y = bfhi(hv0) * sw0 + bb.y;
        float a1x = 0.f, a1y = 0.f, a2x = 0.f, a2y = 0.f, a3x = 0.f, a3y = 0.f;
        float c0x = bflo(hv1) * sw1 + bb.x, c0y = bfhi(hv1) * sw1 + bb.y;
        float c1x = 0.f, c1y = 0.f, c2x = 0.f, c2y = 0.f, c3x = 0.f, c3y = 0.f;

        int dmin = dc0 < dc1 ? dc0 : dc1;
        int e = 0;
        for (; e + 4 <= dmin; e += 4) {              // interleaved: 8 epair + 8 row loads in flight
            int2 p0 = epg[st0 + e];
            int2 p1 = epg[st0 + e + 1];
            int2 p2 = epg[st0 + e + 2];
            int2 p3 = epg[st0 + e + 3];
            int2 q0 = epg[st1 + e];
            int2 q1 = epg[st1 + e + 1];
            int2 q2 = epg[st1 + e + 2];
            int2 q3 = epg[st1 + e + 3];
            unsigned r0 = Hg[(size_t)p0.x * 64 + lane];
            unsigned r1 = Hg[(size_t)p1.x * 64 + lane];
            unsigned r2 = Hg[(size_t)p2.x * 64 + lane];
            unsigned r3 = Hg[(size_t)p3.x * 64 + lane];
            unsigned s0 = Hg[(size_t)q0.x * 64 + lane];
            unsigned s1 = Hg[(size_t)q1.x * 64 + lane];
            unsigned s2 = Hg[(size_t)q2.x * 64 + lane];
            unsigned s3 = Hg[(size_t)q3.x * 64 + lane];
            float w0 = __int_as_float(p0.y), w1 = __int_as_float(p1.y);
            float w2 = __int_as_float(p2.y), w3 = __int_as_float(p3.y);
            float u0 = __int_as_float(q0.y), u1 = __int_as_float(q1.y);
            float u2 = __int_as_float(q2.y), u3 = __int_as_float(q3.y);
            a0x = fmaf(bflo(r0), w0, a0x); a0y = fmaf(bfhi(r0), w0, a0y);
            a1x = fmaf(bflo(r1), w1, a1x); a1y = fmaf(bfhi(r1), w1, a1y);
            a2x = fmaf(bflo(r2), w2, a2x); a2y = fmaf(bfhi(r2), w2, a2y);
            a3x = fmaf(bflo(r3), w3, a3x); a3y = fmaf(bfhi(r3), w3, a3y);
            c0x = fmaf(bflo(s0), u0, c0x); c0y = fmaf(bfhi(s0), u0, c0y);
            c1x = fmaf(bflo(s1), u1, c1x); c1y = fmaf(bfhi(s1), u1, c1y);
            c2x = fmaf(bflo(s2), u2, c2x); c2y = fmaf(bfhi(s2), u2, c2y);
            c3x = fmaf(bflo(s3), u3, c3x); c3y = fmaf(bfhi(s3), u3, c3y);
        }
        // node0 tail
        int e0 = e;
        for (; e0 + 4 <= dc0; e0 += 4) {
            int2 p0 = epg[st0 + e0];
            int2 p1 = epg[st0 + e0 + 1];
            int2 p2 = epg[st0 + e0 + 2];
            int2 p3 = epg[st0 + e0 + 3];
            unsigned r0 = Hg[(size_t)p0.x * 64 + lane];
            unsigned r1 = Hg[(size_t)p1.x * 64 + lane];
            unsigned r2 = Hg[(size_t)p2.x * 64 + lane];
            unsigned r3 = Hg[(size_t)p3.x * 64 + lane];
            float w0 = __int_as_float(p0.y), w1 = __int_as_float(p1.y);
            float w2 = __int_as_float(p2.y), w3 = __int_as_float(p3.y);
            a0x = fmaf(bflo(r0), w0, a0x); a0y = fmaf(bfhi(r0), w0, a0y);
            a1x = fmaf(bflo(r1), w1, a1x); a1y = fmaf(bfhi(r1), w1, a1y);
            a2x = fmaf(bflo(r2), w2, a2x); a2y = fmaf(bfhi(r2), w2, a2y);
            a3x = fmaf(bflo(r3), w3, a3x); a3y = fmaf(bfhi(r3), w3, a3y);
        }
        for (; e0 < dc0; ++e0) {
            int2 p0 = epg[st0 + e0];
            unsigned r0 = Hg[(size_t)p0.x * 64 + lane];
            float w0 = __int_as_float(p0.y);
            a0x = fmaf(bflo(r0), w0, a0x); a0y = fmaf(bfhi(r0), w0, a0y);
        }
        // node1 tail
        int e1 = e;
        for (; e1 + 4 <= dc1; e1 += 4) {
            int2 q0 = epg[st1 + e1];
            int2 q1 = epg[st1 + e1 + 1];
            int2 q2 = epg[st1 + e1 + 2];
            int2 q3 = epg[st1 + e1 + 3];
            unsigned s0 = Hg[(size_t)q0.x * 64 + lane];
            unsigned s1 = Hg[(size_t)q1.x * 64 + lane];
            unsigned s2 = Hg[(size_t)q2.x * 64 + lane];
            unsigned s3 = Hg[(size_t)q3.x * 64 + lane];
            float u0 = __int_as_float(q0.y), u1 = __int_as_float(q1.y);
            float u2 = __int_as_float(q2.y), u3 = __int_as_float(q3.y);
            c0x = fmaf(bflo(s0), u0, c0x); c0y = fmaf(bfhi(s0), u0, c0y);
            c1x = fmaf(bflo(s1), u1, c1x); c1y = fmaf(bfhi(s1), u1, c1y);
            c2x = fmaf(bflo(s2), u2, c2x); c2y = fmaf(bfhi(s2), u2, c2y);
            c3x = fmaf(bflo(s3), u3, c3x); c3y = fmaf(bfhi(s3), u3, c3y);
        }
        for (; e1 < dc1; ++e1) {
            int2 q0 = epg[st1 + e1];
            unsigned s0 = Hg[(size_t)q0.x * 64 + lane];
            float u0 = __int_as_float(q0.y);
            c0x = fmaf(bflo(s0), u0, c0x); c0y = fmaf(bfhi(s0), u0, c0y);
        }

        float ax = (a0x + a1x) + (a2x + a3x);
        float ay = (a0y + a1y) + (a2y + a3y);
        float cx = (c0x + c1x) + (c2x + c3x);
        float cy = (c0y + c1y) + (c2y + c3y);
        float tx0 = tanhf(ax), ty0 = tanhf(ay);
        float tx1 = tanhf(cx), ty1 = tanhf(cy);
        if (POOL) {
            px += tx0 + tx1;
            py += ty0 + ty1;
        } else {
            Tout[(size_t)(g * Nn + n0) * 64 + lane] = ((unsigned)f2bf(ty0) << 16) | (unsigned)f2bf(tx0);
            Tout[(size_t)(g * Nn + n1) * 64 + lane] = ((unsigned)f2bf(ty1) << 16) | (unsigned)f2bf(tx1);
        }
    }
    if (POOL) {
        atomicAdd(&pooled[g * Cc + lane * 2], px);
        atomicAdd(&pooled[g * Cc + lane * 2 + 1], py);
    }
}

// ---------------- qkv: one wave per output column (coalesced rows + shuffle reduce) -------
__global__ __launch_bounds__(1024) void k_qkv(const float* __restrict__ pooled, const float* __restrict__ in_w,
                                              const float* __restrict__ in_b, float* __restrict__ qkvb)
{
    int t = threadIdx.x, lane = t & 63, wv = t >> 6;
    int c = blockIdx.x * 16 + wv;          // 24 blocks * 16 waves = 384 columns
    const float* wr = in_w + c * Cc;
    float w0 = wr[lane], w1 = wr[64 + lane];
    float bias = in_b[c];
    for (int i = 0; i < Gn; ++i) {
        float p = fmaf(pooled[i * Cc + lane], w0, pooled[i * Cc + 64 + lane] * w1);
        #pragma unroll
        for (int off2 = 32; off2 > 0; off2 >>= 1) p += __shfl_xor(p, off2);
        if (lane == 0) qkvb[i * 384 + c] = p + bias;
    }
}

// ---------------- attn: per-head block, pure LDS ----------------
__global__ __launch_bounds__(1024) void k_attn(const float* __restrict__ qkvb, float* __restrict__ ob)
{
    __shared__ float q[64][33], kk[64][33], v[64][33];
    __shared__ float S[64][64];
    int h = blockIdx.x, t = threadIdx.x;

    for (int idx = t; idx < 2048; idx += 1024) {
        int i = idx >> 5, cc = idx & 31;
        q[i][cc]  = qkvb[i * 384 + h * 32 + cc];
        kk[i][cc] = qkvb[i * 384 + 128 + h * 32 + cc];
        v[i][cc]  = qkvb[i * 384 + 256 + h * 32 + cc];
    }
    __syncthreads();

    for (int idx = t; idx < 4096; idx += 1024) {
        int i = idx >> 6, jj = idx & 63;
        float acc = 0.f;
        #pragma unroll
        for (int d2 = 0; d2 < 32; ++d2) acc = fmaf(q[i][d2], kk[jj][d2], acc);
        S[i][jj] = acc * 0.17677669529663687f;
    }
    __syncthreads();

    int lane = t & 63, w = t >> 6;
    for (int r = w; r < 64; r += 16) {
        float val = S[r][lane];
        float m = val;
        #pragma unroll
        for (int off = 32; off > 0; off >>= 1) m = fmaxf(m, __shfl_xor(m, off));
        float e2 = expf(val - m);
        float ssum = e2;
        #pragma unroll
        for (int off = 32; off > 0; off >>= 1) ssum += __shfl_xor(ssum, off);
        S[r][lane] = e2 / ssum;
    }
    __syncthreads();

    for (int idx = t; idx < 2048; idx += 1024) {
        int i = idx >> 5, d2 = idx & 31;
        float acc = 0.f;
        #pragma unroll 4
        for (int k2 = 0; k2 < 64; ++k2) acc = fmaf(S[i][k2], v[k2][d2], acc);
        ob[i * Cc + h * 32 + d2] = acc;
    }
}

// ------ tail+final: one graph per block, 512 threads, 8-acc ILP split-K MLP ---------------
__global__ __launch_bounds__(512) void k_tailfinal(const float* __restrict__ ob, const float* __restrict__ out_w,
                                                   const float* __restrict__ out_b, const float* __restrict__ mw1,
                                                   const float* __restrict__ mb1, const float* __restrict__ mw2,
                                                   const float* __restrict__ mb2, const float* __restrict__ ln2g,
                                                   const float* __restrict__ ln2b, const float* __restrict__ lw,
                                                   const float* __restrict__ lb, float* __restrict__ repr,
                                                   int* __restrict__ ctr, float* __restrict__ out)
{
    __shared__ float sob[128];
    __shared__ float sxatt[128];
    __shared__ float sm1p[2][256];
    __shared__ float sm1[256];
    __shared__ float sp2[4][128];
    __shared__ float yb[128];
    __shared__ int slast;
    int g = blockIdx.x;                     // 64 blocks, 1 graph each
    int t = threadIdx.x, lane = t & 63, wv = t >> 6;

    if (t < 128) sob[t] = ob[(size_t)g * Cc + t];
    __syncthreads();

    // out-proj: wave per column (coalesced out_w rows), 16 cols/wave
    {
        float o0 = sob[lane], o1 = sob[64 + lane];
        for (int c = wv; c < Cc; c += 8) {
            const float* wr = out_w + c * Cc;
            float p = fmaf(o0, wr[lane], o1 * wr[64 + lane]);
            #pragma unroll
            for (int off = 32; off > 0; off >>= 1) p += __shfl_xor(p, off);
            if (lane == 0) sxatt[c] = p + out_b[c];
        }
    }
    __syncthreads();

    // mlp1: 512 threads = 256 cols x 2 K-halves; 8 independent acc chains
    {
        int jc = t & 255, half = t >> 8;
        int k0b = half * 64;
        float a[8];
        #pragma unroll
        for (int u = 0; u < 8; ++u) a[u] = 0.f;
        for (int k0 = k0b; k0 < k0b + 64; k0 += 8) {
            #pragma unroll
            for (int u = 0; u < 8; ++u)
                a[u] = fmaf(sxatt[k0 + u], mw1[(size_t)(k0 + u) * HIDn + jc], a[u]);
        }
        sm1p[half][jc] = ((a[0] + a[1]) + (a[2] + a[3])) + ((a[4] + a[5]) + (a[6] + a[7]));
        __syncthreads();
        if (t < 256) sm1[t] = fmaxf(sm1p[0][t] + sm1p[1][t] + mb1[t], 0.f);
    }
    __syncthreads();

    // mlp2: 512 threads = 128 cols x 4 K-quarters; 8 independent acc chains
    {
        int c = t & 127, q = t >> 7;
        int j0b = q * 64;
        float a[8];
        #pragma unroll
        for (int u = 0; u < 8; ++u) a[u] = 0.f;
        for (int j0 = j0b; j0 < j0b + 64; j0 += 8) {
            #pragma unroll
            for (int u = 0; u < 8; ++u)
                a[u] = fmaf(sm1[j0 + u], mw2[(size_t)(j0 + u) * Cc + c], a[u]);
        }
        sp2[q][c] = ((a[0] + a[1]) + (a[2] + a[3])) + ((a[4] + a[5]) + (a[6] + a[7]));
        __syncthreads();
        if (t < 128) yb[t] = sxatt[t] + (sp2[0][t] + sp2[1][t]) + (sp2[2][t] + sp2[3][t]) + mb2[t];
    }
    __syncthreads();

    // LN + relu (wave 0) + atomic accumulate into repr
    if (t < 64) {
        float v0 = yb[lane], v1 = yb[64 + lane];
        float s = v0 + v1;
        #pragma unroll
        for (int off = 32; off > 0; off >>= 1) s += __shfl_xor(s, off);
        float mu = s * (1.f / 128.f);
        float d0 = v0 - mu, d1 = v1 - mu;
        float vv = d0 * d0 + d1 * d1;
        #pragma unroll
        for (int off = 32; off > 0; off >>= 1) vv += __shfl_xor(vv, off);
        float rstd = rsqrtf(vv * (1.f / 128.f) + EPSf);
        float z0 = fmaxf(d0 * rstd * ln2g[lane] + ln2b[lane], 0.f);
        float z1 = fmaxf(d1 * rstd * ln2g[64 + lane] + ln2b[64 + lane], 0.f);
        atomicAdd(&repr[lane], z0);
        atomicAdd(&repr[64 + lane], z1);
    }

    // completion: last-arriving block reduces repr -> logits
    __threadfence();
    __syncthreads();
    if (t == 0) slast = atomicAdd(ctr, 1);
    __syncthreads();
    if (slast == 63) {
        __threadfence();
        __shared__ float r0s[128], r1s[128];
        if (t < 128) {
            float r = __hip_atomic_load(&repr[t], __ATOMIC_RELAXED, __HIP_MEMORY_SCOPE_AGENT);
            r0s[t] = r * lw[t * 2 + 0];
            r1s[t] = r * lw[t * 2 + 1];
        }
        __syncthreads();
        for (int s2 = 64; s2 > 0; s2 >>= 1) {
            if (t < s2) { r0s[t] += r0s[t + s2]; r1s[t] += r1s[t + s2]; }
            __syncthreads();
        }
        if (t == 0) { out[0] = r0s[0] + lb[0]; out[1] = r1s[0] + lb[1]; }
    }
}

extern "C" void kernel_launch(void* const* d_in, const int* in_sizes, int n_in,
                              void* d_out, int out_size, void* d_ws, size_t ws_size,
                              hipStream_t stream)
{
    const float* x     = (const float*)d_in[0];
    const int*   ei    = (const int*)d_in[1];
    const float* W0    = (const float*)d_in[2];
    const float* b0    = (const float*)d_in[3];
    const float* W1    = (const float*)d_in[4];
    const float* b1    = (const float*)d_in[5];
    const float* in_w  = (const float*)d_in[6];
    const float* in_b  = (const float*)d_in[7];
    const float* out_w = (const float*)d_in[8];
    const float* out_b = (const float*)d_in[9];
    const float* ln2g  = (const float*)d_in[10];
    const float* ln2b  = (const float*)d_in[11];
    const float* mw1   = (const float*)d_in[12];
    const float* mb1   = (const float*)d_in[13];
    const float* mw2   = (const float*)d_in[14];
    const float* mb2   = (const float*)d_in[15];
    const float* lw    = (const float*)d_in[16];
    const float* lb    = (const float*)d_in[17];
    float* out = (float*)d_out;
    (void)in_sizes; (void)n_in; (void)out_size; (void)ws_size;

    char* ws = (char*)d_ws;
    size_t off = 0;
    auto carve = [&](size_t bytes) { size_t o = off; off += (bytes + 255) & ~(size_t)255; return o; };
    size_t o_ni    = carve((size_t)Gn * Nn * 16);
    size_t o_ep    = carve((size_t)Gn * En * 8);
    size_t o_pool  = carve((size_t)Gn * Cc * 4);
    size_t o_qkv   = carve((size_t)Gn * 384 * 4);
    size_t o_ob    = carve((size_t)Gn * Cc * 4);
    size_t o_repr  = carve((size_t)Cc * 4);
    size_t o_ctr   = carve(256);
    size_t o_W0t   = carve((size_t)Cc * Cc * 2);
    size_t o_W1t   = carve((size_t)Cc * Cc * 2);
    size_t o_H     = carve((size_t)Gn * Nn * Cc * 2);
    size_t o_T     = carve((size_t)Gn * Nn * Cc * 2);

    int4*  ninfo  = (int4*)(ws + o_ni);
    int2*  epair  = (int2*)(ws + o_ep);
    float* pooled = (float*)(ws + o_pool);
    float* qkvb   = (float*)(ws + o_qkv);
    float* ob     = (float*)(ws + o_ob);
    float* repr   = (float*)(ws + o_repr);
    int*   ctr    = (int*)(ws + o_ctr);
    unsigned short* Wt0g = (unsigned short*)(ws + o_W0t);
    unsigned short* Wt1g = (unsigned short*)(ws + o_W1t);
    unsigned short* H  = (unsigned short*)(ws + o_H);
    unsigned short* T  = (unsigned short*)(ws + o_T);

    k_pre<<<66, 256, 0, stream>>>(ei, W0, W1, ninfo, epair, pooled, repr, ctr, Wt0g, Wt1g);
    k_gemm<0><<<1024, 256, 0, stream>>>(x, Wt0g, H);
    k_combine<0><<<2048, 256, 0, stream>>>((const unsigned*)H, epair, ninfo, b0, (unsigned*)T, nullptr);
    k_gemm<1><<<1024, 256, 0, stream>>>(T, Wt1g, H);
    k_combine<1><<<2048, 256, 0, stream>>>((const unsigned*)H, epair, ninfo, b1, nullptr, pooled);
    k_qkv<<<24, 1024, 0, stream>>>(pooled, in_w, in_b, qkvb);
    k_attn<<<4, 1024, 0, stream>>>(qkvb, ob);
    k_tailfinal<<<64, 512, 0, stream>>>(ob, out_w, out_b, mw1, mb1, mw2, mb2, ln2g, ln2b,
                                        lw, lb, repr, ctr, out);
}

// Round 13
// 176.258 us; speedup vs baseline: 1.0054x; 1.0054x over previous
//
#include <hip/hip_runtime.h>
#include <math.h>

#define Gn 64
#define Nn 1000
#define En 8192
#define Cc 128
#define HIDn 256
#define EPSf 1e-5f

typedef __attribute__((ext_vector_type(8))) short bh8;
typedef __attribute__((ext_vector_type(4))) float fx4;

__device__ __forceinline__ unsigned short f2bf(float f) {
    unsigned u = __float_as_uint(f);
    u += 0x7fffu + ((u >> 16) & 1u);
    return (unsigned short)(u >> 16);
}
__device__ __forceinline__ float bflo(unsigned u) { return __uint_as_float(u << 16); }
__device__ __forceinline__ float bfhi(unsigned u) { return __uint_as_float(u & 0xffff0000u); }

// ---- fused front: blocks 0..63 prep(graph b) | 64..1087 gemm0 (16/graph) | 1088 W1->Wt1g ----
__global__ __launch_bounds__(256) void k_g0p(const int* __restrict__ ei, const float* __restrict__ X,
                                             const float* __restrict__ W0, const float* __restrict__ W1,
                                             int4* __restrict__ ninfo, int2* __restrict__ epair,
                                             float* __restrict__ pooled, float* __restrict__ repr,
                                             int* __restrict__ bars,
                                             unsigned short* __restrict__ Wt1g,
                                             unsigned short* __restrict__ Hout)
{
    __shared__ __align__(16) short Wt[128][136];   // gemm/transpose staging; prep aliases it
    __shared__ int wsum[4];
    int t = threadIdx.x;
    int b = blockIdx.x;

    if (b < 64) {
        // ---------------- prep (wave-scan CSR build), graph b on XCD b%8 ----------------
        int* curs = (int*)&Wt[0][0];                       // 4KB
        float* dinv_s = (float*)((char*)&Wt[0][0] + 4096); // 4KB
        int g = b;
        const int* srcp = ei + (size_t)g * 2 * En;
        const int* dstp = srcp + En;
        int lane = t & 63, wv = t >> 6;

        #pragma unroll
        for (int j = 0; j < 4; ++j) curs[t * 4 + j] = 0;
        __syncthreads();
        for (int e = t; e < En; e += 256) atomicAdd(&curs[dstp[e]], 1);
        __syncthreads();

        int base = t * 4;
        int d0 = curs[base], d1 = curs[base + 1], d2 = curs[base + 2], d3 = curs[base + 3];
        int s = d0 + d1 + d2 + d3;
        int v = s;
        #pragma unroll
        for (int off = 1; off <= 32; off <<= 1) {
            int u = __shfl_up(v, off);
            if (lane >= off) v += u;
        }
        if (lane == 63) wsum[wv] = v;
        __syncthreads();
        int woff = 0;
        #pragma unroll
        for (int w = 0; w < 4; ++w) if (w < wv) woff += wsum[w];
        int e0 = woff + v - s;
        int e1 = e0 + d0, e2 = e1 + d1, e3 = e2 + d2;
        float dv0 = rsqrtf((float)d0 + 1.f), dv1 = rsqrtf((float)d1 + 1.f);
        float dv2 = rsqrtf((float)d2 + 1.f), dv3 = rsqrtf((float)d3 + 1.f);
        curs[base] = e0; curs[base + 1] = e1; curs[base + 2] = e2; curs[base + 3] = e3;
        dinv_s[base] = dv0; dinv_s[base + 1] = dv1; dinv_s[base + 2] = dv2; dinv_s[base + 3] = dv3;
        if (base < Nn)     ninfo[g * Nn + base]     = make_int4(e0, d0, __float_as_int(dv0 * dv0), 0);
        if (base + 1 < Nn) ninfo[g * Nn + base + 1] = make_int4(e1, d1, __float_as_int(dv1 * dv1), 0);
        if (base + 2 < Nn) ninfo[g * Nn + base + 2] = make_int4(e2, d2, __float_as_int(dv2 * dv2), 0);
        if (base + 3 < Nn) ninfo[g * Nn + base + 3] = make_int4(e3, d3, __float_as_int(dv3 * dv3), 0);
        __syncthreads();

        for (int e = t; e < En; e += 256) {
            int dd = dstp[e], ss = srcp[e];
            int p = atomicAdd(&curs[dd], 1);
            float w = dinv_s[ss] * dinv_s[dd];
            epair[(size_t)g * En + p] = make_int2(ss, __float_as_int(w));
        }
        if (t < Cc) pooled[g * Cc + t] = 0.f;      // accumulated by k_combine<1>
        if (g == 0 && t < Cc) repr[t] = 0.f;       // accumulated by k_head
        if (g == 0 && t < 4) bars[t] = 0;          // k_head barriers + completion ctr
        return;
    }

    if (b == 1088) {
        // ---- W1 fp32 [k][n] -> Wt1g bf16 [n][k] (consumed by k_gemm1) ----
        for (int idx = t; idx < 16384; idx += 256) {
            int kI = idx >> 7, n = idx & 127;
            Wt[n][kI] = (short)f2bf(W1[idx]);
        }
        __syncthreads();
        for (int idx = t; idx < 2048; idx += 256) {
            int n = idx >> 4, kc = idx & 15;
            *(bh8*)(Wt1g + (size_t)idx * 8) = *(const bh8*)&Wt[n][kc * 8];
        }
        return;
    }

    // ---------------- gemm0: H[g] = bf16(X[g] @ W0), in-block W0 transpose ----------------
    int bb = b - 64;
    int xcd = bb & 7, gg = (bb >> 3) & 7, rblk = bb >> 6;   // graph on XCD g%8; rblk 0..15
    int g = xcd + 8 * gg;
    for (int idx = t; idx < 16384; idx += 256) {
        int kI = idx >> 7, n = idx & 127;
        Wt[n][kI] = (short)f2bf(W0[idx]);
    }
    __syncthreads();

    int wave = t >> 6, l = t & 63;
    int lr = l & 15, lg = l >> 4;
    const float* Xf = X + (size_t)g * Nn * Cc;
    unsigned short* Hg = Hout + (size_t)g * Nn * Cc;

    int rbase = rblk * 64 + wave * 16;
    int r = rbase + lr;
    bool ok = r < Nn;
    bh8 af[4];
    #pragma unroll
    for (int ks = 0; ks < 4; ++ks) {
        if (ok) {
            const float* xp = Xf + (size_t)r * Cc + ks * 32 + lg * 8;
            fx4 a0 = *(const fx4*)xp;
            fx4 a1 = *(const fx4*)(xp + 4);
            bh8 av;
            av[0] = (short)f2bf(a0[0]); av[1] = (short)f2bf(a0[1]);
            av[2] = (short)f2bf(a0[2]); av[3] = (short)f2bf(a0[3]);
            av[4] = (short)f2bf(a1[0]); av[5] = (short)f2bf(a1[1]);
            av[6] = (short)f2bf(a1[2]); av[7] = (short)f2bf(a1[3]);
            af[ks] = av;
        } else af[ks] = bh8{0, 0, 0, 0, 0, 0, 0, 0};
    }
    fx4 acc[8];
    #pragma unroll
    for (int ct = 0; ct < 8; ++ct) acc[ct] = fx4{0.f, 0.f, 0.f, 0.f};
    #pragma unroll
    for (int ks = 0; ks < 4; ++ks) {
        #pragma unroll
        for (int ct = 0; ct < 8; ++ct) {
            bh8 bfr = *(const bh8*)(&Wt[ct * 16 + lr][ks * 32 + lg * 8]);
            acc[ct] = __builtin_amdgcn_mfma_f32_16x16x32_bf16(af[ks], bfr, acc[ct], 0, 0, 0);
        }
    }
    // C/D layout: col = ct*16 + (lane&15), row = rbase + (lane>>4)*4 + reg
    #pragma unroll
    for (int ct = 0; ct < 8; ++ct) {
        #pragma unroll
        for (int rg = 0; rg < 4; ++rg) {
            int row = rbase + lg * 4 + rg;
            if (row < Nn) Hg[(size_t)row * Cc + ct * 16 + lr] = f2bf(acc[ct][rg]);
        }
    }
}

// ------ gemm1: H[g] = bf16(T[g] @ W1), 16 blocks/graph, pre-transposed bf16 W1 ----------
__global__ __launch_bounds__(256) void k_gemm1(const unsigned short* __restrict__ Xh,
                                               const unsigned short* __restrict__ Wtg,
                                               unsigned short* __restrict__ Hout)
{
    __shared__ __align__(16) short Wt[128][136];
    int b = blockIdx.x;
    int xcd = b & 7, gg = (b >> 3) & 7, rblk = b >> 6;
    int g = xcd + 8 * gg;
    int t = threadIdx.x;
    for (int idx = t; idx < 2048; idx += 256) {
        int n = idx >> 4, kc = idx & 15;
        bh8 v = *(const bh8*)(Wtg + (size_t)idx * 8);
        *(bh8*)&Wt[n][kc * 8] = v;
    }
    __syncthreads();

    int wave = t >> 6, l = t & 63;
    int lr = l & 15, lg = l >> 4;
    const short* Xg = (const short*)Xh + (size_t)g * Nn * Cc;
    unsigned short* Hg = Hout + (size_t)g * Nn * Cc;

    int rbase = rblk * 64 + wave * 16;
    int r = rbase + lr;
    bool ok = r < Nn;
    bh8 af[4];
    #pragma unroll
    for (int ks = 0; ks < 4; ++ks) {
        if (ok) af[ks] = *(const bh8*)(Xg + (size_t)r * Cc + ks * 32 + lg * 8);
        else    af[ks] = bh8{0, 0, 0, 0, 0, 0, 0, 0};
    }
    fx4 acc[8];
    #pragma unroll
    for (int ct = 0; ct < 8; ++ct) acc[ct] = fx4{0.f, 0.f, 0.f, 0.f};
    #pragma unroll
    for (int ks = 0; ks < 4; ++ks) {
        #pragma unroll
        for (int ct = 0; ct < 8; ++ct) {
            bh8 bfr = *(const bh8*)(&Wt[ct * 16 + lr][ks * 32 + lg * 8]);
            acc[ct] = __builtin_amdgcn_mfma_f32_16x16x32_bf16(af[ks], bfr, acc[ct], 0, 0, 0);
        }
    }
    #pragma unroll
    for (int ct = 0; ct < 8; ++ct) {
        #pragma unroll
        for (int rg = 0; rg < 4; ++rg) {
            int row = rbase + lg * 4 + rg;
            if (row < Nn) Hg[(size_t)row * Cc + ct * 16 + lr] = f2bf(acc[ct][rg]);
        }
    }
}

// ------- combine: tanh(b + selfw*H[n] + sum_e w_e*H[src_e]); 4-deep early-exit gather ------
template<int POOL>
__global__ __launch_bounds__(256) void k_combine(const unsigned* __restrict__ Hb, const int2* __restrict__ epair,
                                                 const int4* __restrict__ ninfo, const float* __restrict__ bias,
                                                 unsigned* __restrict__ Tout, float* __restrict__ pooled)
{
    int b = blockIdx.x;
    int xcd = b & 7, j = b >> 3;
    int g = xcd + 8 * (j & 7);     // same XCD as this graph's GEMM blocks
    int blk = j >> 3;              // 0..31
    int wave = threadIdx.x >> 6, lane = threadIdx.x & 63;
    const unsigned* Hg = Hb + (size_t)g * Nn * 64;   // rows of 64 uint = 128 bf16
    const int2* epg = epair + (size_t)g * En;
    const int4* nig = ninfo + (size_t)g * Nn;
    float2 bb = *(const float2*)(bias + lane * 2);
    float px = 0.f, py = 0.f;
    for (int n = blk * 4 + wave; n < Nn; n += 128) {
        int4 ni = nig[n];
        int st = ni.x, dc = ni.y;
        float sw = __int_as_float(ni.z);
        unsigned hv = Hg[(size_t)n * 64 + lane];
        float a0x = bflo(hv) * sw + bb.x, a0y = bfhi(hv) * sw + bb.y;
        float a1x = 0.f, a1y = 0.f, a2x = 0.f, a2y = 0.f, a3x = 0.f, a3y = 0.f;
        int e = 0;
        for (; e + 4 <= dc; e += 4) {
            int2 p0 = epg[st + e];
            int2 p1 = epg[st + e + 1];
            int2 p2 = epg[st + e + 2];
            int2 p3 = epg[st + e + 3];
            unsigned r0 = Hg[(size_t)p0.x * 64 + lane];
            unsigned r1 = Hg[(size_t)p1.x * 64 + lane];
            unsigned r2 = Hg[(size_t)p2.x * 64 + lane];
            unsigned r3 = Hg[(size_t)p3.x * 64 + lane];
            float w0 = __int_as_float(p0.y), w1 = __int_as_float(p1.y);
            float w2 = __int_as_float(p2.y), w3 = __int_as_float(p3.y);
            a0x = fmaf(bflo(r0), w0, a0x); a0y = fmaf(bfhi(r0), w0, a0y);
            a1x = fmaf(bflo(r1), w1, a1x); a1y = fmaf(bfhi(r1), w1, a1y);
            a2x = fmaf(bflo(r2), w2, a2x); a2y = fmaf(bfhi(r2), w2, a2y);
            a3x = fmaf(bflo(r3), w3, a3x); a3y = fmaf(bfhi(r3), w3, a3y);
        }
        for (; e < dc; ++e) {
            int2 p0 = epg[st + e];
            unsigned r0 = Hg[(size_t)p0.x * 64 + lane];
            float w0 = __int_as_float(p0.y);
            a0x = fmaf(bflo(r0), w0, a0x); a0y = fmaf(bfhi(r0), w0, a0y);
        }
        float ax = (a0x + a1x) + (a2x + a3x);
        float ay = (a0y + a1y) + (a2y + a3y);
        float tx = tanhf(ax), ty = tanhf(ay);
        if (POOL) { px += tx; py += ty; }
        else Tout[(size_t)(g * Nn + n) * 64 + lane] = ((unsigned)f2bf(ty) << 16) | (unsigned)f2bf(tx);
    }
    if (POOL) {
        atomicAdd(&pooled[g * Cc + lane * 2], px);
        atomicAdd(&pooled[g * Cc + lane * 2 + 1], py);
    }
}

// ------ fused head: 64 blocks x 512; qkv -> spin-barrier -> attn(blocks 0..3) -> spin-barrier
//        -> per-graph tail -> last block logits. 64 blocks always co-resident (<= 256 CUs).
__global__ __launch_bounds__(512) void k_head(const float* __restrict__ pooled, const float* __restrict__ in_w,
                                              const float* __restrict__ in_b, const float* __restrict__ out_w,
                                              const float* __restrict__ out_b, const float* __restrict__ mw1,
                                              const float* __restrict__ mb1, const float* __restrict__ mw2,
                                              const float* __restrict__ mb2, const float* __restrict__ ln2g,
                                              const float* __restrict__ ln2b, const float* __restrict__ lw,
                                              const float* __restrict__ lb, float* __restrict__ qkvb,
                                              float* __restrict__ ob, float* __restrict__ repr,
                                              int* __restrict__ bars, float* __restrict__ out)
{
    __shared__ float spool[128];
    __shared__ float q[64][33], kk[64][33], vv[64][33];
    __shared__ float S[64][64];
    __shared__ float sob[128], sxatt[128], sm1p[2][256], sm1[256], sp2[4][128], yb[128];
    __shared__ int slast;
    int g = blockIdx.x, t = threadIdx.x, lane = t & 63, wv = t >> 6;

    // ---- stage 1: qkv row for graph g (AGENT stores for cross-XCD visibility) ----
    if (t < 128) spool[t] = pooled[g * Cc + t];
    __syncthreads();
    {
        float p0 = spool[lane], p1 = spool[64 + lane];
        for (int c = wv; c < 384; c += 8) {
            const float* wr = in_w + c * Cc;
            float p = fmaf(p0, wr[lane], p1 * wr[64 + lane]);
            #pragma unroll
            for (int off = 32; off > 0; off >>= 1) p += __shfl_xor(p, off);
            if (lane == 0)
                __hip_atomic_store(&qkvb[g * 384 + c], p + in_b[c],
                                   __ATOMIC_RELAXED, __HIP_MEMORY_SCOPE_AGENT);
        }
    }
    __syncthreads();
    if (t == 0) {
        __hip_atomic_fetch_add(&bars[0], 1, __ATOMIC_RELEASE, __HIP_MEMORY_SCOPE_AGENT);
        while (__hip_atomic_load(&bars[0], __ATOMIC_ACQUIRE, __HIP_MEMORY_SCOPE_AGENT) < Gn) {}
    }
    __syncthreads();

    // ---- stage 2: attention, blocks 0..3 (one head each) ----
    if (g < 4) {
        int h = g;
        for (int idx = t; idx < 2048; idx += 512) {
            int i = idx >> 5, cc = idx & 31;
            q[i][cc]  = __hip_atomic_load(&qkvb[i * 384 + h * 32 + cc],
                                          __ATOMIC_RELAXED, __HIP_MEMORY_SCOPE_AGENT);
            kk[i][cc] = __hip_atomic_load(&qkvb[i * 384 + 128 + h * 32 + cc],
                                          __ATOMIC_RELAXED, __HIP_MEMORY_SCOPE_AGENT);
            vv[i][cc] = __hip_atomic_load(&qkvb[i * 384 + 256 + h * 32 + cc],
                                          __ATOMIC_RELAXED, __HIP_MEMORY_SCOPE_AGENT);
        }
        __syncthreads();
        for (int idx = t; idx < 4096; idx += 512) {
            int i = idx >> 6, jj = idx & 63;
            float acc = 0.f;
            #pragma unroll
            for (int d2 = 0; d2 < 32; ++d2) acc = fmaf(q[i][d2], kk[jj][d2], acc);
            S[i][jj] = acc * 0.17677669529663687f;
        }
        __syncthreads();
        for (int r = wv; r < 64; r += 8) {
            float val = S[r][lane];
            float m = val;
            #pragma unroll
            for (int off = 32; off > 0; off >>= 1) m = fmaxf(m, __shfl_xor(m, off));
            float e2 = expf(val - m);
            float ssum = e2;
            #pragma unroll
            for (int off = 32; off > 0; off >>= 1) ssum += __shfl_xor(ssum, off);
            S[r][lane] = e2 / ssum;
        }
        __syncthreads();
        for (int idx = t; idx < 2048; idx += 512) {
            int i = idx >> 5, d2 = idx & 31;
            float acc = 0.f;
            #pragma unroll 4
            for (int k2 = 0; k2 < 64; ++k2) acc = fmaf(S[i][k2], vv[k2][d2], acc);
            __hip_atomic_store(&ob[i * Cc + h * 32 + d2], acc,
                               __ATOMIC_RELAXED, __HIP_MEMORY_SCOPE_AGENT);
        }
    }
    __syncthreads();
    if (t == 0) {
        __hip_atomic_fetch_add(&bars[1], 1, __ATOMIC_RELEASE, __HIP_MEMORY_SCOPE_AGENT);
        while (__hip_atomic_load(&bars[1], __ATOMIC_ACQUIRE, __HIP_MEMORY_SCOPE_AGENT) < Gn) {}
    }
    __syncthreads();

    // ---- stage 3: tail for graph g ----
    if (t < 128) sob[t] = __hip_atomic_load(&ob[(size_t)g * Cc + t],
                                            __ATOMIC_RELAXED, __HIP_MEMORY_SCOPE_AGENT);
    __syncthreads();

    {   // out-proj: wave per column (coalesced out_w rows)
        float o0 = sob[lane], o1 = sob[64 + lane];
        for (int c = wv; c < Cc; c += 8) {
            const float* wr = out_w + c * Cc;
            float p = fmaf(o0, wr[lane], o1 * wr[64 + lane]);
            #pragma unroll
            for (int off = 32; off > 0; off >>= 1) p += __shfl_xor(p, off);
            if (lane == 0) sxatt[c] = p + out_b[c];
        }
    }
    __syncthreads();

    {   // mlp1: 512 threads = 256 cols x 2 K-halves; 8 independent acc chains
        int jc = t & 255, half = t >> 8;
        int k0b = half * 64;
        float a[8];
        #pragma unroll
        for (int u = 0; u < 8; ++u) a[u] = 0.f;
        for (int k0 = k0b; k0 < k0b + 64; k0 += 8) {
            #pragma unroll
            for (int u = 0; u < 8; ++u)
                a[u] = fmaf(sxatt[k0 + u], mw1[(size_t)(k0 + u) * HIDn + jc], a[u]);
        }
        sm1p[half][jc] = ((a[0] + a[1]) + (a[2] + a[3])) + ((a[4] + a[5]) + (a[6] + a[7]));
        __syncthreads();
        if (t < 256) sm1[t] = fmaxf(sm1p[0][t] + sm1p[1][t] + mb1[t], 0.f);
    }
    __syncthreads();

    {   // mlp2: 512 threads = 128 cols x 4 K-quarters; 8 independent acc chains
        int c = t & 127, qq = t >> 7;
        int j0b = qq * 64;
        float a[8];
        #pragma unroll
        for (int u = 0; u < 8; ++u) a[u] = 0.f;
        for (int j0 = j0b; j0 < j0b + 64; j0 += 8) {
            #pragma unroll
            for (int u = 0; u < 8; ++u)
                a[u] = fmaf(sm1[j0 + u], mw2[(size_t)(j0 + u) * Cc + c], a[u]);
        }
        sp2[qq][c] = ((a[0] + a[1]) + (a[2] + a[3])) + ((a[4] + a[5]) + (a[6] + a[7]));
        __syncthreads();
        if (t < 128) yb[t] = sxatt[t] + (sp2[0][t] + sp2[1][t]) + (sp2[2][t] + sp2[3][t]) + mb2[t];
    }
    __syncthreads();

    // LN + relu (wave 0) + atomic accumulate into repr
    if (t < 64) {
        float v0 = yb[lane], v1 = yb[64 + lane];
        float s = v0 + v1;
        #pragma unroll
        for (int off = 32; off > 0; off >>= 1) s += __shfl_xor(s, off);
        float mu = s * (1.f / 128.f);
        float d0 = v0 - mu, d1 = v1 - mu;
        float vvr = d0 * d0 + d1 * d1;
        #pragma unroll
        for (int off = 32; off > 0; off >>= 1) vvr += __shfl_xor(vvr, off);
        float rstd = rsqrtf(vvr * (1.f / 128.f) + EPSf);
        float z0 = fmaxf(d0 * rstd * ln2g[lane] + ln2b[lane], 0.f);
        float z1 = fmaxf(d1 * rstd * ln2g[64 + lane] + ln2b[64 + lane], 0.f);
        atomicAdd(&repr[lane], z0);
        atomicAdd(&repr[64 + lane], z1);
    }

    // completion: last-arriving block reduces repr -> logits
    __threadfence();
    __syncthreads();
    if (t == 0) slast = atomicAdd(&bars[2], 1);
    __syncthreads();
    if (slast == 63) {
        __threadfence();
        __shared__ float r0s[128], r1s[128];
        if (t < 128) {
            float r = __hip_atomic_load(&repr[t], __ATOMIC_RELAXED, __HIP_MEMORY_SCOPE_AGENT);
            r0s[t] = r * lw[t * 2 + 0];
            r1s[t] = r * lw[t * 2 + 1];
        }
        __syncthreads();
        for (int s2 = 64; s2 > 0; s2 >>= 1) {
            if (t < s2) { r0s[t] += r0s[t + s2]; r1s[t] += r1s[t + s2]; }
            __syncthreads();
        }
        if (t == 0) { out[0] = r0s[0] + lb[0]; out[1] = r1s[0] + lb[1]; }
    }
}

extern "C" void kernel_launch(void* const* d_in, const int* in_sizes, int n_in,
                              void* d_out, int out_size, void* d_ws, size_t ws_size,
                              hipStream_t stream)
{
    const float* x     = (const float*)d_in[0];
    const int*   ei    = (const int*)d_in[1];
    const float* W0    = (const float*)d_in[2];
    const float* b0    = (const float*)d_in[3];
    const float* W1    = (const float*)d_in[4];
    const float* b1    = (const float*)d_in[5];
    const float* in_w  = (const float*)d_in[6];
    const float* in_b  = (const float*)d_in[7];
    const float* out_w = (const float*)d_in[8];
    const float* out_b = (const float*)d_in[9];
    const float* ln2g  = (const float*)d_in[10];
    const float* ln2b  = (const float*)d_in[11];
    const float* mw1   = (const float*)d_in[12];
    const float* mb1   = (const float*)d_in[13];
    const float* mw2   = (const float*)d_in[14];
    const float* mb2   = (const float*)d_in[15];
    const float* lw    = (const float*)d_in[16];
    const float* lb    = (const float*)d_in[17];
    float* out = (float*)d_out;
    (void)in_sizes; (void)n_in; (void)out_size; (void)ws_size;

    char* ws = (char*)d_ws;
    size_t off = 0;
    auto carve = [&](size_t bytes) { size_t o = off; off += (bytes + 255) & ~(size_t)255; return o; };
    size_t o_ni    = carve((size_t)Gn * Nn * 16);
    size_t o_ep    = carve((size_t)Gn * En * 8);
    size_t o_pool  = carve((size_t)Gn * Cc * 4);
    size_t o_qkv   = carve((size_t)Gn * 384 * 4);
    size_t o_ob    = carve((size_t)Gn * Cc * 4);
    size_t o_repr  = carve((size_t)Cc * 4);
    size_t o_bars  = carve(256);
    size_t o_W1t   = carve((size_t)Cc * Cc * 2);
    size_t o_H     = carve((size_t)Gn * Nn * Cc * 2);
    size_t o_T     = carve((size_t)Gn * Nn * Cc * 2);

    int4*  ninfo  = (int4*)(ws + o_ni);
    int2*  epair  = (int2*)(ws + o_ep);
    float* pooled = (float*)(ws + o_pool);
    float* qkvb   = (float*)(ws + o_qkv);
    float* ob     = (float*)(ws + o_ob);
    float* repr   = (float*)(ws + o_repr);
    int*   bars   = (int*)(ws + o_bars);
    unsigned short* Wt1g = (unsigned short*)(ws + o_W1t);
    unsigned short* H  = (unsigned short*)(ws + o_H);
    unsigned short* T  = (unsigned short*)(ws + o_T);

    k_g0p<<<1089, 256, 0, stream>>>(ei, x, W0, W1, ninfo, epair, pooled, repr, bars, Wt1g, H);
    k_combine<0><<<2048, 256, 0, stream>>>((const unsigned*)H, epair, ninfo, b0, (unsigned*)T, nullptr);
    k_gemm1<<<1024, 256, 0, stream>>>(T, Wt1g, H);
    k_combine<1><<<2048, 256, 0, stream>>>((const unsigned*)H, epair, ninfo, b1, nullptr, pooled);
    k_head<<<64, 512, 0, stream>>>(pooled, in_w, in_b, out_w, out_b, mw1, mb1, mw2, mb2,
                                   ln2g, ln2b, lw, lb, qkvb, ob, repr, bars, out);
}

// Round 14
// 159.680 us; speedup vs baseline: 1.1097x; 1.1038x over previous
//
#include <hip/hip_runtime.h>
#include <math.h>

#define Gn 64
#define Nn 1000
#define En 8192
#define Cc 128
#define HIDn 256
#define EPSf 1e-5f

typedef __attribute__((ext_vector_type(8))) short bh8;
typedef __attribute__((ext_vector_type(4))) float fx4;

__device__ __forceinline__ unsigned short f2bf(float f) {
    unsigned u = __float_as_uint(f);
    u += 0x7fffu + ((u >> 16) & 1u);
    return (unsigned short)(u >> 16);
}
__device__ __forceinline__ float bflo(unsigned u) { return __uint_as_float(u << 16); }
__device__ __forceinline__ float bfhi(unsigned u) { return __uint_as_float(u & 0xffff0000u); }

// ---- fused front: blocks 0..63 prep(graph b) | 64..1087 gemm0 (16/graph) | 1088 W1->Wt1g ----
__global__ __launch_bounds__(256) void k_g0p(const int* __restrict__ ei, const float* __restrict__ X,
                                             const float* __restrict__ W0, const float* __restrict__ W1,
                                             int4* __restrict__ ninfo, int2* __restrict__ epair,
                                             float* __restrict__ pooled, float* __restrict__ repr,
                                             int* __restrict__ bars,
                                             unsigned short* __restrict__ Wt1g,
                                             unsigned short* __restrict__ Hout)
{
    __shared__ __align__(16) short Wt[128][136];   // gemm/transpose staging; prep aliases it
    __shared__ int wsum[4];
    int t = threadIdx.x;
    int b = blockIdx.x;

    if (b < 64) {
        // ---------------- prep (wave-scan CSR build), graph b on XCD b%8 ----------------
        int* curs = (int*)&Wt[0][0];                       // 4KB
        float* dinv_s = (float*)((char*)&Wt[0][0] + 4096); // 4KB
        int g = b;
        const int* srcp = ei + (size_t)g * 2 * En;
        const int* dstp = srcp + En;
        int lane = t & 63, wv = t >> 6;

        #pragma unroll
        for (int j = 0; j < 4; ++j) curs[t * 4 + j] = 0;
        __syncthreads();
        for (int e = t; e < En; e += 256) atomicAdd(&curs[dstp[e]], 1);
        __syncthreads();

        int base = t * 4;
        int d0 = curs[base], d1 = curs[base + 1], d2 = curs[base + 2], d3 = curs[base + 3];
        int s = d0 + d1 + d2 + d3;
        int v = s;
        #pragma unroll
        for (int off = 1; off <= 32; off <<= 1) {
            int u = __shfl_up(v, off);
            if (lane >= off) v += u;
        }
        if (lane == 63) wsum[wv] = v;
        __syncthreads();
        int woff = 0;
        #pragma unroll
        for (int w = 0; w < 4; ++w) if (w < wv) woff += wsum[w];
        int e0 = woff + v - s;
        int e1 = e0 + d0, e2 = e1 + d1, e3 = e2 + d2;
        float dv0 = rsqrtf((float)d0 + 1.f), dv1 = rsqrtf((float)d1 + 1.f);
        float dv2 = rsqrtf((float)d2 + 1.f), dv3 = rsqrtf((float)d3 + 1.f);
        curs[base] = e0; curs[base + 1] = e1; curs[base + 2] = e2; curs[base + 3] = e3;
        dinv_s[base] = dv0; dinv_s[base + 1] = dv1; dinv_s[base + 2] = dv2; dinv_s[base + 3] = dv3;
        if (base < Nn)     ninfo[g * Nn + base]     = make_int4(e0, d0, __float_as_int(dv0 * dv0), 0);
        if (base + 1 < Nn) ninfo[g * Nn + base + 1] = make_int4(e1, d1, __float_as_int(dv1 * dv1), 0);
        if (base + 2 < Nn) ninfo[g * Nn + base + 2] = make_int4(e2, d2, __float_as_int(dv2 * dv2), 0);
        if (base + 3 < Nn) ninfo[g * Nn + base + 3] = make_int4(e3, d3, __float_as_int(dv3 * dv3), 0);
        __syncthreads();

        for (int e = t; e < En; e += 256) {
            int dd = dstp[e], ss = srcp[e];
            int p = atomicAdd(&curs[dd], 1);
            float w = dinv_s[ss] * dinv_s[dd];
            epair[(size_t)g * En + p] = make_int2(ss, __float_as_int(w));
        }
        if (t < Cc) pooled[g * Cc + t] = 0.f;      // accumulated by k_combine<1>
        if (g == 0 && t < Cc) repr[t] = 0.f;       // accumulated by k_tailfinal
        if (g == 0 && t < 4) bars[t] = 0;          // completion ctr for k_tailfinal
        return;
    }

    if (b == 1088) {
        // ---- W1 fp32 [k][n] -> Wt1g bf16 [n][k] (consumed by k_gemm1) ----
        for (int idx = t; idx < 16384; idx += 256) {
            int kI = idx >> 7, n = idx & 127;
            Wt[n][kI] = (short)f2bf(W1[idx]);
        }
        __syncthreads();
        for (int idx = t; idx < 2048; idx += 256) {
            int n = idx >> 4, kc = idx & 15;
            *(bh8*)(Wt1g + (size_t)idx * 8) = *(const bh8*)&Wt[n][kc * 8];
        }
        return;
    }

    // ---------------- gemm0: H[g] = bf16(X[g] @ W0), in-block W0 transpose ----------------
    int bb = b - 64;
    int xcd = bb & 7, gg = (bb >> 3) & 7, rblk = bb >> 6;   // graph on XCD g%8; rblk 0..15
    int g = xcd + 8 * gg;
    for (int idx = t; idx < 16384; idx += 256) {
        int kI = idx >> 7, n = idx & 127;
        Wt[n][kI] = (short)f2bf(W0[idx]);
    }
    __syncthreads();

    int wave = t >> 6, l = t & 63;
    int lr = l & 15, lg = l >> 4;
    const float* Xf = X + (size_t)g * Nn * Cc;
    unsigned short* Hg = Hout + (size_t)g * Nn * Cc;

    int rbase = rblk * 64 + wave * 16;
    int r = rbase + lr;
    bool ok = r < Nn;
    bh8 af[4];
    #pragma unroll
    for (int ks = 0; ks < 4; ++ks) {
        if (ok) {
            const float* xp = Xf + (size_t)r * Cc + ks * 32 + lg * 8;
            fx4 a0 = *(const fx4*)xp;
            fx4 a1 = *(const fx4*)(xp + 4);
            bh8 av;
            av[0] = (short)f2bf(a0[0]); av[1] = (short)f2bf(a0[1]);
            av[2] = (short)f2bf(a0[2]); av[3] = (short)f2bf(a0[3]);
            av[4] = (short)f2bf(a1[0]); av[5] = (short)f2bf(a1[1]);
            av[6] = (short)f2bf(a1[2]); av[7] = (short)f2bf(a1[3]);
            af[ks] = av;
        } else af[ks] = bh8{0, 0, 0, 0, 0, 0, 0, 0};
    }
    fx4 acc[8];
    #pragma unroll
    for (int ct = 0; ct < 8; ++ct) acc[ct] = fx4{0.f, 0.f, 0.f, 0.f};
    #pragma unroll
    for (int ks = 0; ks < 4; ++ks) {
        #pragma unroll
        for (int ct = 0; ct < 8; ++ct) {
            bh8 bfr = *(const bh8*)(&Wt[ct * 16 + lr][ks * 32 + lg * 8]);
            acc[ct] = __builtin_amdgcn_mfma_f32_16x16x32_bf16(af[ks], bfr, acc[ct], 0, 0, 0);
        }
    }
    // C/D layout: col = ct*16 + (lane&15), row = rbase + (lane>>4)*4 + reg
    #pragma unroll
    for (int ct = 0; ct < 8; ++ct) {
        #pragma unroll
        for (int rg = 0; rg < 4; ++rg) {
            int row = rbase + lg * 4 + rg;
            if (row < Nn) Hg[(size_t)row * Cc + ct * 16 + lr] = f2bf(acc[ct][rg]);
        }
    }
}

// ------ gemm1: H[g] = bf16(T[g] @ W1), 16 blocks/graph, pre-transposed bf16 W1 ----------
__global__ __launch_bounds__(256) void k_gemm1(const unsigned short* __restrict__ Xh,
                                               const unsigned short* __restrict__ Wtg,
                                               unsigned short* __restrict__ Hout)
{
    __shared__ __align__(16) short Wt[128][136];
    int b = blockIdx.x;
    int xcd = b & 7, gg = (b >> 3) & 7, rblk = b >> 6;
    int g = xcd + 8 * gg;
    int t = threadIdx.x;
    for (int idx = t; idx < 2048; idx += 256) {
        int n = idx >> 4, kc = idx & 15;
        bh8 v = *(const bh8*)(Wtg + (size_t)idx * 8);
        *(bh8*)&Wt[n][kc * 8] = v;
    }
    __syncthreads();

    int wave = t >> 6, l = t & 63;
    int lr = l & 15, lg = l >> 4;
    const short* Xg = (const short*)Xh + (size_t)g * Nn * Cc;
    unsigned short* Hg = Hout + (size_t)g * Nn * Cc;

    int rbase = rblk * 64 + wave * 16;
    int r = rbase + lr;
    bool ok = r < Nn;
    bh8 af[4];
    #pragma unroll
    for (int ks = 0; ks < 4; ++ks) {
        if (ok) af[ks] = *(const bh8*)(Xg + (size_t)r * Cc + ks * 32 + lg * 8);
        else    af[ks] = bh8{0, 0, 0, 0, 0, 0, 0, 0};
    }
    fx4 acc[8];
    #pragma unroll
    for (int ct = 0; ct < 8; ++ct) acc[ct] = fx4{0.f, 0.f, 0.f, 0.f};
    #pragma unroll
    for (int ks = 0; ks < 4; ++ks) {
        #pragma unroll
        for (int ct = 0; ct < 8; ++ct) {
            bh8 bfr = *(const bh8*)(&Wt[ct * 16 + lr][ks * 32 + lg * 8]);
            acc[ct] = __builtin_amdgcn_mfma_f32_16x16x32_bf16(af[ks], bfr, acc[ct], 0, 0, 0);
        }
    }
    #pragma unroll
    for (int ct = 0; ct < 8; ++ct) {
        #pragma unroll
        for (int rg = 0; rg < 4; ++rg) {
            int row = rbase + lg * 4 + rg;
            if (row < Nn) Hg[(size_t)row * Cc + ct * 16 + lr] = f2bf(acc[ct][rg]);
        }
    }
}

// ------- combine: tanh(b + selfw*H[n] + sum_e w_e*H[src_e]); 4-deep early-exit gather ------
template<int POOL>
__global__ __launch_bounds__(256) void k_combine(const unsigned* __restrict__ Hb, const int2* __restrict__ epair,
                                                 const int4* __restrict__ ninfo, const float* __restrict__ bias,
                                                 unsigned* __restrict__ Tout, float* __restrict__ pooled)
{
    int b = blockIdx.x;
    int xcd = b & 7, j = b >> 3;
    int g = xcd + 8 * (j & 7);     // same XCD as this graph's GEMM blocks
    int blk = j >> 3;              // 0..31
    int wave = threadIdx.x >> 6, lane = threadIdx.x & 63;
    const unsigned* Hg = Hb + (size_t)g * Nn * 64;   // rows of 64 uint = 128 bf16
    const int2* epg = epair + (size_t)g * En;
    const int4* nig = ninfo + (size_t)g * Nn;
    float2 bb = *(const float2*)(bias + lane * 2);
    float px = 0.f, py = 0.f;
    for (int n = blk * 4 + wave; n < Nn; n += 128) {
        int4 ni = nig[n];
        int st = ni.x, dc = ni.y;
        float sw = __int_as_float(ni.z);
        unsigned hv = Hg[(size_t)n * 64 + lane];
        float a0x = bflo(hv) * sw + bb.x, a0y = bfhi(hv) * sw + bb.y;
        float a1x = 0.f, a1y = 0.f, a2x = 0.f, a2y = 0.f, a3x = 0.f, a3y = 0.f;
        int e = 0;
        for (; e + 4 <= dc; e += 4) {
            int2 p0 = epg[st + e];
            int2 p1 = epg[st + e + 1];
            int2 p2 = epg[st + e + 2];
            int2 p3 = epg[st + e + 3];
            unsigned r0 = Hg[(size_t)p0.x * 64 + lane];
            unsigned r1 = Hg[(size_t)p1.x * 64 + lane];
            unsigned r2 = Hg[(size_t)p2.x * 64 + lane];
            unsigned r3 = Hg[(size_t)p3.x * 64 + lane];
            float w0 = __int_as_float(p0.y), w1 = __int_as_float(p1.y);
            float w2 = __int_as_float(p2.y), w3 = __int_as_float(p3.y);
            a0x = fmaf(bflo(r0), w0, a0x); a0y = fmaf(bfhi(r0), w0, a0y);
            a1x = fmaf(bflo(r1), w1, a1x); a1y = fmaf(bfhi(r1), w1, a1y);
            a2x = fmaf(bflo(r2), w2, a2x); a2y = fmaf(bfhi(r2), w2, a2y);
            a3x = fmaf(bflo(r3), w3, a3x); a3y = fmaf(bfhi(r3), w3, a3y);
        }
        for (; e < dc; ++e) {
            int2 p0 = epg[st + e];
            unsigned r0 = Hg[(size_t)p0.x * 64 + lane];
            float w0 = __int_as_float(p0.y);
            a0x = fmaf(bflo(r0), w0, a0x); a0y = fmaf(bfhi(r0), w0, a0y);
        }
        float ax = (a0x + a1x) + (a2x + a3x);
        float ay = (a0y + a1y) + (a2y + a3y);
        float tx = tanhf(ax), ty = tanhf(ay);
        if (POOL) { px += tx; py += ty; }
        else Tout[(size_t)(g * Nn + n) * 64 + lane] = ((unsigned)f2bf(ty) << 16) | (unsigned)f2bf(tx);
    }
    if (POOL) {
        atomicAdd(&pooled[g * Cc + lane * 2], px);
        atomicAdd(&pooled[g * Cc + lane * 2 + 1], py);
    }
}

// ---------------- qkv: one wave per output column (coalesced rows + shuffle reduce) -------
__global__ __launch_bounds__(1024) void k_qkv(const float* __restrict__ pooled, const float* __restrict__ in_w,
                                              const float* __restrict__ in_b, float* __restrict__ qkvb)
{
    int t = threadIdx.x, lane = t & 63, wv = t >> 6;
    int c = blockIdx.x * 16 + wv;          // 24 blocks * 16 waves = 384 columns
    const float* wr = in_w + c * Cc;
    float w0 = wr[lane], w1 = wr[64 + lane];
    float bias = in_b[c];
    for (int i = 0; i < Gn; ++i) {
        float p = fmaf(pooled[i * Cc + lane], w0, pooled[i * Cc + 64 + lane] * w1);
        #pragma unroll
        for (int off2 = 32; off2 > 0; off2 >>= 1) p += __shfl_xor(p, off2);
        if (lane == 0) qkvb[i * 384 + c] = p + bias;
    }
}

// ---------------- attn: per-head block, pure LDS ----------------
__global__ __launch_bounds__(1024) void k_attn(const float* __restrict__ qkvb, float* __restrict__ ob)
{
    __shared__ float q[64][33], kk[64][33], v[64][33];
    __shared__ float S[64][64];
    int h = blockIdx.x, t = threadIdx.x;

    for (int idx = t; idx < 2048; idx += 1024) {
        int i = idx >> 5, cc = idx & 31;
        q[i][cc]  = qkvb[i * 384 + h * 32 + cc];
        kk[i][cc] = qkvb[i * 384 + 128 + h * 32 + cc];
        v[i][cc]  = qkvb[i * 384 + 256 + h * 32 + cc];
    }
    __syncthreads();

    for (int idx = t; idx < 4096; idx += 1024) {
        int i = idx >> 6, jj = idx & 63;
        float acc = 0.f;
        #pragma unroll
        for (int d2 = 0; d2 < 32; ++d2) acc = fmaf(q[i][d2], kk[jj][d2], acc);
        S[i][jj] = acc * 0.17677669529663687f;
    }
    __syncthreads();

    int lane = t & 63, w = t >> 6;
    for (int r = w; r < 64; r += 16) {
        float val = S[r][lane];
        float m = val;
        #pragma unroll
        for (int off = 32; off > 0; off >>= 1) m = fmaxf(m, __shfl_xor(m, off));
        float e2 = expf(val - m);
        float ssum = e2;
        #pragma unroll
        for (int off = 32; off > 0; off >>= 1) ssum += __shfl_xor(ssum, off);
        S[r][lane] = e2 / ssum;
    }
    __syncthreads();

    for (int idx = t; idx < 2048; idx += 1024) {
        int i = idx >> 5, d2 = idx & 31;
        float acc = 0.f;
        #pragma unroll 4
        for (int k2 = 0; k2 < 64; ++k2) acc = fmaf(S[i][k2], v[k2][d2], acc);
        ob[i * Cc + h * 32 + d2] = acc;
    }
}

// ------ tail+final: one graph per block, 512 threads, 8-acc ILP split-K MLP ---------------
__global__ __launch_bounds__(512) void k_tailfinal(const float* __restrict__ ob, const float* __restrict__ out_w,
                                                   const float* __restrict__ out_b, const float* __restrict__ mw1,
                                                   const float* __restrict__ mb1, const float* __restrict__ mw2,
                                                   const float* __restrict__ mb2, const float* __restrict__ ln2g,
                                                   const float* __restrict__ ln2b, const float* __restrict__ lw,
                                                   const float* __restrict__ lb, float* __restrict__ repr,
                                                   int* __restrict__ ctr, float* __restrict__ out)
{
    __shared__ float sob[128];
    __shared__ float sxatt[128];
    __shared__ float sm1p[2][256];
    __shared__ float sm1[256];
    __shared__ float sp2[4][128];
    __shared__ float yb[128];
    __shared__ int slast;
    int g = blockIdx.x;                     // 64 blocks, 1 graph each
    int t = threadIdx.x, lane = t & 63, wv = t >> 6;

    if (t < 128) sob[t] = ob[(size_t)g * Cc + t];
    __syncthreads();

    // out-proj: wave per column (coalesced out_w rows)
    {
        float o0 = sob[lane], o1 = sob[64 + lane];
        for (int c = wv; c < Cc; c += 8) {
            const float* wr = out_w + c * Cc;
            float p = fmaf(o0, wr[lane], o1 * wr[64 + lane]);
            #pragma unroll
            for (int off = 32; off > 0; off >>= 1) p += __shfl_xor(p, off);
            if (lane == 0) sxatt[c] = p + out_b[c];
        }
    }
    __syncthreads();

    // mlp1: 512 threads = 256 cols x 2 K-halves; 8 independent acc chains
    {
        int jc = t & 255, half = t >> 8;
        int k0b = half * 64;
        float a[8];
        #pragma unroll
        for (int u = 0; u < 8; ++u) a[u] = 0.f;
        for (int k0 = k0b; k0 < k0b + 64; k0 += 8) {
            #pragma unroll
            for (int u = 0; u < 8; ++u)
                a[u] = fmaf(sxatt[k0 + u], mw1[(size_t)(k0 + u) * HIDn + jc], a[u]);
        }
        sm1p[half][jc] = ((a[0] + a[1]) + (a[2] + a[3])) + ((a[4] + a[5]) + (a[6] + a[7]));
        __syncthreads();
        if (t < 256) sm1[t] = fmaxf(sm1p[0][t] + sm1p[1][t] + mb1[t], 0.f);
    }
    __syncthreads();

    // mlp2: 512 threads = 128 cols x 4 K-quarters; 8 independent acc chains
    {
        int c = t & 127, q = t >> 7;
        int j0b = q * 64;
        float a[8];
        #pragma unroll
        for (int u = 0; u < 8; ++u) a[u] = 0.f;
        for (int j0 = j0b; j0 < j0b + 64; j0 += 8) {
            #pragma unroll
            for (int u = 0; u < 8; ++u)
                a[u] = fmaf(sm1[j0 + u], mw2[(size_t)(j0 + u) * Cc + c], a[u]);
        }
        sp2[q][c] = ((a[0] + a[1]) + (a[2] + a[3])) + ((a[4] + a[5]) + (a[6] + a[7]));
        __syncthreads();
        if (t < 128) yb[t] = sxatt[t] + (sp2[0][t] + sp2[1][t]) + (sp2[2][t] + sp2[3][t]) + mb2[t];
    }
    __syncthreads();

    // LN + relu (wave 0) + atomic accumulate into repr
    if (t < 64) {
        float v0 = yb[lane], v1 = yb[64 + lane];
        float s = v0 + v1;
        #pragma unroll
        for (int off = 32; off > 0; off >>= 1) s += __shfl_xor(s, off);
        float mu = s * (1.f / 128.f);
        float d0 = v0 - mu, d1 = v1 - mu;
        float vv = d0 * d0 + d1 * d1;
        #pragma unroll
        for (int off = 32; off > 0; off >>= 1) vv += __shfl_xor(vv, off);
        float rstd = rsqrtf(vv * (1.f / 128.f) + EPSf);
        float z0 = fmaxf(d0 * rstd * ln2g[lane] + ln2b[lane], 0.f);
        float z1 = fmaxf(d1 * rstd * ln2g[64 + lane] + ln2b[64 + lane], 0.f);
        atomicAdd(&repr[lane], z0);
        atomicAdd(&repr[64 + lane], z1);
    }

    // completion: last-arriving block reduces repr -> logits
    __threadfence();
    __syncthreads();
    if (t == 0) slast = atomicAdd(ctr, 1);
    __syncthreads();
    if (slast == 63) {
        __threadfence();
        __shared__ float r0s[128], r1s[128];
        if (t < 128) {
            float r = __hip_atomic_load(&repr[t], __ATOMIC_RELAXED, __HIP_MEMORY_SCOPE_AGENT);
            r0s[t] = r * lw[t * 2 + 0];
            r1s[t] = r * lw[t * 2 + 1];
        }
        __syncthreads();
        for (int s2 = 64; s2 > 0; s2 >>= 1) {
            if (t < s2) { r0s[t] += r0s[t + s2]; r1s[t] += r1s[t + s2]; }
            __syncthreads();
        }
        if (t == 0) { out[0] = r0s[0] + lb[0]; out[1] = r1s[0] + lb[1]; }
    }
}

extern "C" void kernel_launch(void* const* d_in, const int* in_sizes, int n_in,
                              void* d_out, int out_size, void* d_ws, size_t ws_size,
                              hipStream_t stream)
{
    const float* x     = (const float*)d_in[0];
    const int*   ei    = (const int*)d_in[1];
    const float* W0    = (const float*)d_in[2];
    const float* b0    = (const float*)d_in[3];
    const float* W1    = (const float*)d_in[4];
    const float* b1    = (const float*)d_in[5];
    const float* in_w  = (const float*)d_in[6];
    const float* in_b  = (const float*)d_in[7];
    const float* out_w = (const float*)d_in[8];
    const float* out_b = (const float*)d_in[9];
    const float* ln2g  = (const float*)d_in[10];
    const float* ln2b  = (const float*)d_in[11];
    const float* mw1   = (const float*)d_in[12];
    const float* mb1   = (const float*)d_in[13];
    const float* mw2   = (const float*)d_in[14];
    const float* mb2   = (const float*)d_in[15];
    const float* lw    = (const float*)d_in[16];
    const float* lb    = (const float*)d_in[17];
    float* out = (float*)d_out;
    (void)in_sizes; (void)n_in; (void)out_size; (void)ws_size;

    char* ws = (char*)d_ws;
    size_t off = 0;
    auto carve = [&](size_t bytes) { size_t o = off; off += (bytes + 255) & ~(size_t)255; return o; };
    size_t o_ni    = carve((size_t)Gn * Nn * 16);
    size_t o_ep    = carve((size_t)Gn * En * 8);
    size_t o_pool  = carve((size_t)Gn * Cc * 4);
    size_t o_qkv   = carve((size_t)Gn * 384 * 4);
    size_t o_ob    = carve((size_t)Gn * Cc * 4);
    size_t o_repr  = carve((size_t)Cc * 4);
    size_t o_bars  = carve(256);
    size_t o_W1t   = carve((size_t)Cc * Cc * 2);
    size_t o_H     = carve((size_t)Gn * Nn * Cc * 2);
    size_t o_T     = carve((size_t)Gn * Nn * Cc * 2);

    int4*  ninfo  = (int4*)(ws + o_ni);
    int2*  epair  = (int2*)(ws + o_ep);
    float* pooled = (float*)(ws + o_pool);
    float* qkvb   = (float*)(ws + o_qkv);
    float* ob     = (float*)(ws + o_ob);
    float* repr   = (float*)(ws + o_repr);
    int*   bars   = (int*)(ws + o_bars);
    unsigned short* Wt1g = (unsigned short*)(ws + o_W1t);
    unsigned short* H  = (unsigned short*)(ws + o_H);
    unsigned short* T  = (unsigned short*)(ws + o_T);

    k_g0p<<<1089, 256, 0, stream>>>(ei, x, W0, W1, ninfo, epair, pooled, repr, bars, Wt1g, H);
    k_combine<0><<<2048, 256, 0, stream>>>((const unsigned*)H, epair, ninfo, b0, (unsigned*)T, nullptr);
    k_gemm1<<<1024, 256, 0, stream>>>(T, Wt1g, H);
    k_combine<1><<<2048, 256, 0, stream>>>((const unsigned*)H, epair, ninfo, b1, nullptr, pooled);
    k_qkv<<<24, 1024, 0, stream>>>(pooled, in_w, in_b, qkvb);
    k_attn<<<4, 1024, 0, stream>>>(qkvb, ob);
    k_tailfinal<<<64, 512, 0, stream>>>(ob, out_w, out_b, mw1, mb1, mw2, mb2, ln2g, ln2b,
                                        lw, lb, repr, &bars[2], out);
}